// Round 2
// baseline (1122.520 us; speedup 1.0000x reference)
//
#include <hip/hip_runtime.h>
#include <hip/hip_fp16.h>
#include <hip/hip_cooperative_groups.h>

namespace cg = cooperative_groups;

#define N_NODES 100000
#define N_EDGES 1600000
#define MSG 16
#define HID 16
#define NT 8
#define NC 32
#define PREP_N 800000       // N*HID/2 packed half2 words == N*MSG/2 m2 words
#define A2_WORDS 1024       // NT*MSG*HID/2 packed half2 words (4 KB)

typedef _Float16 v2h __attribute__((ext_vector_type(2)));

union H2U {
    v2h h;
    unsigned int u;
};

__device__ __forceinline__ float dot2acc(unsigned int a, unsigned int b, float acc) {
    H2U x, y;
    x.u = a; y.u = b;
#if __has_builtin(__builtin_amdgcn_fdot2)
    return __builtin_amdgcn_fdot2(x.h, y.h, acc, false);
#else
    return acc + (float)x.h[0] * (float)y.h[0] + (float)x.h[1] * (float)y.h[1];
#endif
}

__device__ __forceinline__ float fast_sigmoid(float x) {
    return 1.f / (1.f + __expf(-x));
}
__device__ __forceinline__ float fast_tanh(float x) {
    return 2.f / (1.f + __expf(-2.f * x)) - 1.f;
}

// ---------------------------------------------------------------------------
// Phase 1: feat f32 -> packed fp16 mirror; pack edge_table; zero R replica
// accumulators. Grid-stride so it runs under any grid size.
// ---------------------------------------------------------------------------
__device__ __forceinline__ void phase_prep(
    int gtid, int gsz, int R,
    const float* __restrict__ feat,
    const float* __restrict__ edge_table,
    unsigned int* __restrict__ feat16,
    unsigned int* __restrict__ m2r,
    unsigned int* __restrict__ A2) {
    for (int i = gtid; i < PREP_N; i += gsz) {
        float2 f = reinterpret_cast<const float2*>(feat)[i];
        H2U p;
        p.h[0] = (_Float16)f.x;
        p.h[1] = (_Float16)f.y;
        feat16[i] = p.u;
    }
    // zero replicas as uint4 (R*PREP_N words, PREP_N % 4 == 0)
    uint4 z;
    z.x = z.y = z.z = z.w = 0u;
    uint4* mz = reinterpret_cast<uint4*>(m2r);
    int n4 = R * (PREP_N / 4);
    for (int i = gtid; i < n4; i += gsz) mz[i] = z;
    for (int i = gtid; i < A2_WORDS; i += gsz) {
        float2 f = reinterpret_cast<const float2*>(edge_table)[i];
        H2U p;
        p.h[0] = (_Float16)f.x;
        p.h[1] = (_Float16)f.y;
        A2[i] = p.u;
    }
}

// ---------------------------------------------------------------------------
// Phase 2: edge scatter. 8 lanes per edge, lane c computes message pair
// (2c,2c+1) via v_dot2_f32_f16 and fires one packed-f16 atomic into replica
// (e & (R-1)) -- spreads same-destination atomics across R distinct cache
// lines to break memory-side same-line serialization.
// ---------------------------------------------------------------------------
__device__ __forceinline__ void phase_edge(
    long long gtid, long long gsz, int R,
    const int* __restrict__ src,
    const int* __restrict__ dst,
    const int* __restrict__ etype,
    const unsigned int* __restrict__ feat16,
    const unsigned int* __restrict__ A2,
    unsigned int* __restrict__ m2r) {
    const long long total = (long long)N_EDGES * 8;
    unsigned int rmask = (unsigned int)(R - 1);
    for (long long t = gtid; t < total; t += gsz) {
        int e = (int)(t >> 3);
        int c = (int)(t & 7);

        int s = src[e];
        int ty = etype[e];
        const uint4* hp = reinterpret_cast<const uint4*>(feat16 + (size_t)s * 8);
        uint4 h0 = hp[0], h1 = hp[1];
        const uint4* ap = reinterpret_cast<const uint4*>(A2 + ty * 128 + c * 16);
        uint4 a0 = ap[0], a1 = ap[1], a2 = ap[2], a3 = ap[3];

        float r0 = 0.f, r1 = 0.f;
        r0 = dot2acc(h0.x, a0.x, r0); r0 = dot2acc(h0.y, a0.y, r0);
        r0 = dot2acc(h0.z, a0.z, r0); r0 = dot2acc(h0.w, a0.w, r0);
        r0 = dot2acc(h1.x, a1.x, r0); r0 = dot2acc(h1.y, a1.y, r0);
        r0 = dot2acc(h1.z, a1.z, r0); r0 = dot2acc(h1.w, a1.w, r0);
        r1 = dot2acc(h0.x, a2.x, r1); r1 = dot2acc(h0.y, a2.y, r1);
        r1 = dot2acc(h0.z, a2.z, r1); r1 = dot2acc(h0.w, a2.w, r1);
        r1 = dot2acc(h1.x, a3.x, r1); r1 = dot2acc(h1.y, a3.y, r1);
        r1 = dot2acc(h1.z, a3.z, r1); r1 = dot2acc(h1.w, a3.w, r1);

        int d = dst[e];
        H2U p;
        p.h[0] = (_Float16)r0;
        p.h[1] = (_Float16)r1;
        size_t roff = (size_t)((unsigned int)e & rmask) * PREP_N;
#if __has_builtin(__builtin_amdgcn_global_atomic_fadd_v2f16)
        __builtin_amdgcn_global_atomic_fadd_v2f16(
            reinterpret_cast<v2h*>(m2r + roff + (size_t)d * 8 + c), p.h);
#endif
    }
}

// ---------------------------------------------------------------------------
// Phase 3: replica reduction + GRU cell + output projection. One thread per
// node; weights are wave-uniform -> scalar loads. Replica sum in f32.
// ---------------------------------------------------------------------------
__device__ __forceinline__ void phase_node(
    int gtid, int gsz, int R,
    const float* __restrict__ feat,
    const unsigned int* __restrict__ m2r,
    const float* __restrict__ W_ih,
    const float* __restrict__ W_hh,
    const float* __restrict__ b_ih,
    const float* __restrict__ b_hh,
    const float* __restrict__ W_out,
    const float* __restrict__ b_out,
    float* __restrict__ out) {
    for (int n = gtid; n < N_NODES; n += gsz) {
        float mv[MSG], h[HID];
        #pragma unroll
        for (int k = 0; k < MSG; ++k) mv[k] = 0.f;
        for (int r = 0; r < R; ++r) {
            const uint4* mu = reinterpret_cast<const uint4*>(
                m2r + (size_t)r * PREP_N + (size_t)n * 8);
            uint4 a = mu[0], b = mu[1];
            unsigned int w[8] = {a.x, a.y, a.z, a.w, b.x, b.y, b.z, b.w};
            #pragma unroll
            for (int i = 0; i < 8; ++i) {
                H2U hh;
                hh.u = w[i];
                mv[2 * i]     += (float)hh.h[0];
                mv[2 * i + 1] += (float)hh.h[1];
            }
        }
        const float4* f4 = reinterpret_cast<const float4*>(feat + (size_t)n * HID);
        #pragma unroll
        for (int q = 0; q < 4; ++q) {
            float4 v = f4[q];
            h[q * 4 + 0] = v.x; h[q * 4 + 1] = v.y;
            h[q * 4 + 2] = v.z; h[q * 4 + 3] = v.w;
        }

        float srz[2 * HID];
        for (int g = 0; g < 2 * HID; ++g) {
            float ai = 0.f, ah = 0.f;
            const float* wi = W_ih + g * MSG;
            const float* wh = W_hh + g * HID;
            #pragma unroll
            for (int k = 0; k < HID; ++k) {
                ai += wi[k] * mv[k];
                ah += wh[k] * h[k];
            }
            srz[g] = ai + ah + b_ih[g] + b_hh[g];
        }
        float i_n[HID], h_n[HID];
        #pragma unroll
        for (int j = 0; j < HID; ++j) {
            int g = 2 * HID + j;
            float ai = b_ih[g], ah = b_hh[g];
            const float* wi = W_ih + g * MSG;
            const float* wh = W_hh + g * HID;
            #pragma unroll
            for (int k = 0; k < HID; ++k) {
                ai += wi[k] * mv[k];
                ah += wh[k] * h[k];
            }
            i_n[j] = ai;
            h_n[j] = ah;
        }

        float hn[HID];
        #pragma unroll
        for (int j = 0; j < HID; ++j) {
            float r = fast_sigmoid(srz[j]);
            float z = fast_sigmoid(srz[HID + j]);
            float nn = fast_tanh(i_n[j] + r * h_n[j]);
            hn[j] = (1.f - z) * nn + z * h[j];
        }

        float4* op = reinterpret_cast<float4*>(out + (size_t)n * NC);
        #pragma unroll
        for (int c4 = 0; c4 < NC / 4; ++c4) {
            float4 o;
            float* oo = &o.x;
            #pragma unroll
            for (int cc = 0; cc < 4; ++cc) {
                int c = c4 * 4 + cc;
                float acc = b_out[c];
                const float* wo = W_out + c * HID;
                #pragma unroll
                for (int k = 0; k < HID; ++k) acc += wo[k] * hn[k];
                oo[cc] = acc;
            }
            op[c4] = o;
        }
    }
}

// ---------------------------------------------------------------------------
// Fused cooperative kernel: prep -> edge -> node with grid-wide syncs.
// One dispatch instead of three.
// ---------------------------------------------------------------------------
__global__ __launch_bounds__(256, 4) void ggnn_fused(
    const float* feat, const int* src, const int* dst, const int* etype,
    const float* edge_table,
    const float* W_ih, const float* W_hh, const float* b_ih, const float* b_hh,
    const float* W_out, const float* b_out,
    float* out, unsigned int* m2r, unsigned int* feat16, unsigned int* A2,
    int R) {
    cg::grid_group grid = cg::this_grid();
    int gtid = blockIdx.x * 256 + threadIdx.x;
    int gsz = gridDim.x * 256;

    phase_prep(gtid, gsz, R, feat, edge_table, feat16, m2r, A2);
    __threadfence();
    grid.sync();
    phase_edge((long long)gtid, (long long)gsz, R, src, dst, etype, feat16, A2, m2r);
    __threadfence();
    grid.sync();
    phase_node(gtid, gsz, R, feat, m2r, W_ih, W_hh, b_ih, b_hh, W_out, b_out, out);
}

// ---------------------------------------------------------------------------
// Standalone fallback kernels (same phases, 3 launches) if cooperative
// launch is unavailable.
// ---------------------------------------------------------------------------
__global__ __launch_bounds__(256) void ggnn_prep_s(
    const float* feat, const float* edge_table,
    unsigned int* feat16, unsigned int* m2r, unsigned int* A2, int R) {
    phase_prep(blockIdx.x * 256 + threadIdx.x, gridDim.x * 256, R,
               feat, edge_table, feat16, m2r, A2);
}

__global__ __launch_bounds__(256) void ggnn_edge_s(
    const int* src, const int* dst, const int* etype,
    const unsigned int* feat16, const unsigned int* A2,
    unsigned int* m2r, int R) {
    phase_edge((long long)(blockIdx.x * 256 + threadIdx.x),
               (long long)gridDim.x * 256, R, src, dst, etype, feat16, A2, m2r);
}

__global__ __launch_bounds__(256) void ggnn_node_s(
    const float* feat, const unsigned int* m2r,
    const float* W_ih, const float* W_hh, const float* b_ih, const float* b_hh,
    const float* W_out, const float* b_out, float* out, int R) {
    phase_node(blockIdx.x * 256 + threadIdx.x, gridDim.x * 256, R,
               feat, m2r, W_ih, W_hh, b_ih, b_hh, W_out, b_out, out);
}

extern "C" void kernel_launch(void* const* d_in, const int* in_sizes, int n_in,
                              void* d_out, int out_size, void* d_ws, size_t ws_size,
                              hipStream_t stream) {
    const float* feat       = (const float*)d_in[0];
    const int*   src        = (const int*)d_in[1];
    const int*   dst        = (const int*)d_in[2];
    const int*   etype      = (const int*)d_in[3];
    const float* edge_table = (const float*)d_in[4];
    const float* W_ih       = (const float*)d_in[5];
    const float* W_hh       = (const float*)d_in[6];
    const float* b_ih       = (const float*)d_in[7];
    const float* b_hh       = (const float*)d_in[8];
    const float* W_out      = (const float*)d_in[9];
    const float* b_out      = (const float*)d_in[10];
    float* out = (float*)d_out;

    // Pick largest replica count (power of 2, <=8) that fits the workspace.
    int R = 8;
    while (R > 1 &&
           ((size_t)R * PREP_N + PREP_N + A2_WORDS) * sizeof(unsigned int) > ws_size)
        R >>= 1;

    unsigned int* m2r    = (unsigned int*)d_ws;
    unsigned int* feat16 = m2r + (size_t)R * PREP_N;
    unsigned int* A2     = feat16 + PREP_N;

    // One-time occupancy/CU query for the cooperative grid (host-side only).
    static int coopBlocks = -2;   // -2 = not yet queried, -1 = unavailable
    if (coopBlocks == -2) {
        int maxB = 0;
        hipError_t oe = hipOccupancyMaxActiveBlocksPerMultiprocessor(
            &maxB, ggnn_fused, 256, 0);
        int cus = 256;
        hipDeviceProp_t prop;
        if (hipGetDeviceProperties(&prop, 0) == hipSuccess &&
            prop.multiProcessorCount > 0)
            cus = prop.multiProcessorCount;
        if (oe == hipSuccess && maxB > 0) {
            if (maxB > 8) maxB = 8;
            coopBlocks = maxB * cus;
        } else {
            coopBlocks = -1;
        }
    }

    if (coopBlocks > 0) {
        void* args[] = {
            (void*)&feat, (void*)&src, (void*)&dst, (void*)&etype,
            (void*)&edge_table,
            (void*)&W_ih, (void*)&W_hh, (void*)&b_ih, (void*)&b_hh,
            (void*)&W_out, (void*)&b_out,
            (void*)&out, (void*)&m2r, (void*)&feat16, (void*)&A2, (void*)&R
        };
        hipError_t le = hipLaunchCooperativeKernel(
            reinterpret_cast<const void*>(ggnn_fused),
            dim3((unsigned)coopBlocks), dim3(256), args, 0, stream);
        if (le == hipSuccess) return;
        coopBlocks = -1;   // remember failure, fall through to separate path
    }

    // Fallback: 3 separate launches.
    int zwork = R * (PREP_N / 4);                 // dominant prep loop
    int pblocks = (zwork + 255) / 256;
    ggnn_prep_s<<<pblocks, 256, 0, stream>>>(feat, edge_table, feat16, m2r, A2, R);

    long long ethreads = (long long)N_EDGES * 8;  // 12.8M
    int eblocks = (int)((ethreads + 255) / 256);  // 50000
    ggnn_edge_s<<<eblocks, 256, 0, stream>>>(src, dst, etype, feat16, A2, m2r, R);

    int nblocks = (N_NODES + 255) / 256;          // 391
    ggnn_node_s<<<nblocks, 256, 0, stream>>>(feat, m2r, W_ih, W_hh, b_ih, b_hh,
                                             W_out, b_out, out, R);
}

// Round 3
// 319.965 us; speedup vs baseline: 3.5083x; 3.5083x over previous
//
#include <hip/hip_runtime.h>
#include <hip/hip_fp16.h>

#define N_NODES 100000
#define N_EDGES 1600000
#define MSG 16
#define HID 16
#define NT 8
#define NC 32
#define PREP_N 800000       // N*HID/2 packed half2 words == N*MSG/2 m2 words
#define A2_WORDS 1024       // NT*MSG*HID/2 packed half2 words (4 KB)

// Binned two-pass message reduction:
#define BINW 512            // nodes per bin (dst >> 9)
#define NBIN 200            // ceil(100000/512)=196, padded
#define BCAP 12288          // per-bin record capacity (mean 8192, sigma~90)
#define CHUNK 4096          // edges per block in the binning pass

typedef _Float16 v2h __attribute__((ext_vector_type(2)));

union H2U {
    v2h h;
    unsigned int u;
};

__device__ __forceinline__ float dot2acc(unsigned int a, unsigned int b, float acc) {
    H2U x, y;
    x.u = a; y.u = b;
#if __has_builtin(__builtin_amdgcn_fdot2)
    return __builtin_amdgcn_fdot2(x.h, y.h, acc, false);
#else
    return acc + (float)x.h[0] * (float)y.h[0] + (float)x.h[1] * (float)y.h[1];
#endif
}

__device__ __forceinline__ float fast_sigmoid(float x) {
    return 1.f / (1.f + __expf(-x));
}
__device__ __forceinline__ float fast_tanh(float x) {
    return 2.f / (1.f + __expf(-2.f * x)) - 1.f;
}

// ---------------------------------------------------------------------------
// Prep: feat f32 -> packed fp16 mirror; pack edge_table to fp16.
// Binned path: zero bincnt. Fallback path: zero m2.
// ---------------------------------------------------------------------------
__global__ __launch_bounds__(256) void ggnn_prep(
    const float* __restrict__ feat,
    const float* __restrict__ edge_table,
    unsigned int* __restrict__ feat16,
    unsigned int* __restrict__ m2z,     // null in binned path
    unsigned int* __restrict__ A2,
    unsigned int* __restrict__ bincnt) { // null in fallback path
    int i = blockIdx.x * 256 + threadIdx.x;
    if (i < PREP_N) {
        float2 f = reinterpret_cast<const float2*>(feat)[i];
        H2U p;
        p.h[0] = (_Float16)f.x;
        p.h[1] = (_Float16)f.y;
        feat16[i] = p.u;
        if (m2z) m2z[i] = 0u;
    }
    if (i < A2_WORDS) {
        float2 f = reinterpret_cast<const float2*>(edge_table)[i];
        H2U p;
        p.h[0] = (_Float16)f.x;
        p.h[1] = (_Float16)f.y;
        A2[i] = p.u;
    }
    if (bincnt && i < 256) bincnt[i] = 0u;
}

// ---------------------------------------------------------------------------
// Pass A: LDS-staged counting sort of edges into NBIN dst-range bins.
// Each block: 4096 edges -> local histogram -> prefix scan -> one global
// reservation atomic per touched bin -> LDS scatter -> coalesced flush of
// contiguous per-bin runs. Record = [dstlo:9][etype:3][src:17] (29 bits).
// Replaces 12.8M fabric atomics with ~78K reservations + ~13 MB of
// mostly-coalesced writes.
// ---------------------------------------------------------------------------
__global__ __launch_bounds__(256) void ggnn_binA(
    const int* __restrict__ src,
    const int* __restrict__ dst,
    const int* __restrict__ etype,
    unsigned int* __restrict__ bincnt,
    unsigned int* __restrict__ binbuf) {
    __shared__ unsigned int   recs[CHUNK];     // 16 KB
    __shared__ unsigned int   sorted[CHUNK];   // 16 KB
    __shared__ unsigned short binof[CHUNK];    // 8 KB
    __shared__ unsigned int   hist[256];
    __shared__ unsigned int   incl[256];       // inclusive scan
    __shared__ unsigned int   base[256];       // global base per bin
    __shared__ unsigned int   cursor[256];     // LDS scatter cursor

    int tid = threadIdx.x;
    int e0 = blockIdx.x * CHUNK;
    int total = N_EDGES - e0;
    if (total > CHUNK) total = CHUNK;

    hist[tid] = 0u;
    __syncthreads();

    // 1) read edges, build records, local histogram
    for (int i = tid; i < total; i += 256) {
        int g = e0 + i;
        unsigned int d = (unsigned int)dst[g];
        unsigned int s = (unsigned int)src[g];
        unsigned int t = (unsigned int)etype[g];
        unsigned int bin = d >> 9;
        unsigned int rec = ((d & 511u) << 20) | (t << 17) | s;
        recs[i] = rec;
        binof[i] = (unsigned short)bin;
        atomicAdd(&hist[bin], 1u);
    }
    __syncthreads();

    // 2) inclusive prefix scan (Hillis-Steele over 256)
    incl[tid] = hist[tid];
    __syncthreads();
    for (int off = 1; off < 256; off <<= 1) {
        unsigned int v = incl[tid] + (tid >= off ? incl[tid - off] : 0u);
        __syncthreads();
        incl[tid] = v;
        __syncthreads();
    }

    // 3) reserve global segments; init scatter cursors (exclusive prefix)
    if (hist[tid] > 0u)
        base[tid] = atomicAdd(&bincnt[tid], hist[tid]);
    cursor[tid] = incl[tid] - hist[tid];
    __syncthreads();

    // 4) scatter records into bin-sorted LDS order
    for (int i = tid; i < total; i += 256) {
        unsigned int b = binof[i];
        unsigned int p = atomicAdd(&cursor[b], 1u);
        sorted[p] = recs[i];
    }
    __syncthreads();

    // 5) coalesced flush: position -> bin via binary search on incl[]
    for (int p = tid; p < total; p += 256) {
        int lo = 0, hi = 255;
        while (lo < hi) {
            int mid = (lo + hi) >> 1;
            if (incl[mid] > (unsigned int)p) hi = mid; else lo = mid + 1;
        }
        unsigned int b = (unsigned int)lo;
        unsigned int off = (unsigned int)p - (incl[b] - hist[b]);
        unsigned int gpos = base[b] + off;
        if (gpos < BCAP)
            binbuf[(size_t)b * BCAP + gpos] = sorted[p];
    }
}

// ---------------------------------------------------------------------------
// Pass B: pull. One block per bin (512 threads, 8 lanes per record).
// Lane c computes message pair (2c,2c+1) via the proven dot2 pattern and
// accumulates into a block-exclusive LDS f32 array (bins partition dst
// space -> zero global atomics). Coalesced half2 flush of m2.
// ---------------------------------------------------------------------------
__global__ __launch_bounds__(512) void ggnn_pull2(
    const unsigned int* __restrict__ bincnt,
    const unsigned int* __restrict__ binbuf,
    const unsigned int* __restrict__ feat16,
    const unsigned int* __restrict__ A2,
    unsigned int* __restrict__ m2) {
    __shared__ float acc[BINW * MSG];   // 32 KB

    int b = blockIdx.x;
    int tid = threadIdx.x;

    for (int i = tid; i < BINW * MSG; i += 512) acc[i] = 0.f;
    __syncthreads();

    int cnt = (int)bincnt[b];
    if (cnt > BCAP) cnt = BCAP;
    const unsigned int* seg = binbuf + (size_t)b * BCAP;
    int c = tid & 7;

    for (int i0 = tid >> 3; i0 < cnt; i0 += 64) {
        unsigned int rec = seg[i0];          // 8 lanes broadcast same word
        int s   = (int)(rec & 0x1FFFFu);
        int t   = (int)((rec >> 17) & 7u);
        int dlo = (int)(rec >> 20);

        const uint4* hp = reinterpret_cast<const uint4*>(feat16 + (size_t)s * 8);
        uint4 h0 = hp[0], h1 = hp[1];
        const uint4* ap = reinterpret_cast<const uint4*>(A2 + t * 128 + c * 16);
        uint4 a0 = ap[0], a1 = ap[1], a2 = ap[2], a3 = ap[3];

        float r0 = 0.f, r1 = 0.f;
        r0 = dot2acc(h0.x, a0.x, r0); r0 = dot2acc(h0.y, a0.y, r0);
        r0 = dot2acc(h0.z, a0.z, r0); r0 = dot2acc(h0.w, a0.w, r0);
        r0 = dot2acc(h1.x, a1.x, r0); r0 = dot2acc(h1.y, a1.y, r0);
        r0 = dot2acc(h1.z, a1.z, r0); r0 = dot2acc(h1.w, a1.w, r0);
        r1 = dot2acc(h0.x, a2.x, r1); r1 = dot2acc(h0.y, a2.y, r1);
        r1 = dot2acc(h0.z, a2.z, r1); r1 = dot2acc(h0.w, a2.w, r1);
        r1 = dot2acc(h1.x, a3.x, r1); r1 = dot2acc(h1.y, a3.y, r1);
        r1 = dot2acc(h1.z, a3.z, r1); r1 = dot2acc(h1.w, a3.w, r1);

        atomicAdd(&acc[dlo * MSG + 2 * c],     r0);
        atomicAdd(&acc[dlo * MSG + 2 * c + 1], r1);
    }
    __syncthreads();

    // flush: BINW nodes x 8 half2 words, coalesced, block-exclusive
    int n0 = b * BINW;
    for (int idx = tid; idx < BINW * 8; idx += 512) {
        int node = idx >> 3;
        int w = idx & 7;
        int n = n0 + node;
        if (n < N_NODES) {
            H2U p;
            p.h[0] = (_Float16)acc[node * MSG + 2 * w];
            p.h[1] = (_Float16)acc[node * MSG + 2 * w + 1];
            m2[(size_t)n * 8 + w] = p.u;
        }
    }
}

// ---------------------------------------------------------------------------
// Fallback edge kernel (proven round-0 atomic scatter) — used only if the
// workspace is too small for the binned path.
// ---------------------------------------------------------------------------
__global__ __launch_bounds__(256) void ggnn_edge(
    const int* __restrict__ src,
    const int* __restrict__ dst,
    const int* __restrict__ etype,
    const unsigned int* __restrict__ feat16,
    const unsigned int* __restrict__ A2,
    unsigned int* __restrict__ m2) {
    int tid = blockIdx.x * 256 + threadIdx.x;
    int e = tid >> 3;
    if (e >= N_EDGES) return;
    int c = tid & 7;

    int s = src[e];
    int t = etype[e];
    const uint4* hp = reinterpret_cast<const uint4*>(feat16 + (size_t)s * 8);
    uint4 h0 = hp[0], h1 = hp[1];
    const uint4* ap = reinterpret_cast<const uint4*>(A2 + t * 128 + c * 16);
    uint4 a0 = ap[0], a1 = ap[1], a2 = ap[2], a3 = ap[3];

    float r0 = 0.f, r1 = 0.f;
    r0 = dot2acc(h0.x, a0.x, r0); r0 = dot2acc(h0.y, a0.y, r0);
    r0 = dot2acc(h0.z, a0.z, r0); r0 = dot2acc(h0.w, a0.w, r0);
    r0 = dot2acc(h1.x, a1.x, r0); r0 = dot2acc(h1.y, a1.y, r0);
    r0 = dot2acc(h1.z, a1.z, r0); r0 = dot2acc(h1.w, a1.w, r0);
    r1 = dot2acc(h0.x, a2.x, r1); r1 = dot2acc(h0.y, a2.y, r1);
    r1 = dot2acc(h0.z, a2.z, r1); r1 = dot2acc(h0.w, a2.w, r1);
    r1 = dot2acc(h1.x, a3.x, r1); r1 = dot2acc(h1.y, a3.y, r1);
    r1 = dot2acc(h1.z, a3.z, r1); r1 = dot2acc(h1.w, a3.w, r1);

    int d = dst[e];
    H2U p;
    p.h[0] = (_Float16)r0;
    p.h[1] = (_Float16)r1;
#if __has_builtin(__builtin_amdgcn_global_atomic_fadd_v2f16)
    __builtin_amdgcn_global_atomic_fadd_v2f16(
        reinterpret_cast<v2h*>(m2 + (size_t)d * 8 + c), p.h);
#endif
}

// ---------------------------------------------------------------------------
// Node kernel: GRU cell + output projection. One thread per node; weights
// are wave-uniform -> scalar loads. (Unchanged, proven.)
// ---------------------------------------------------------------------------
__global__ __launch_bounds__(256) void ggnn_node(
    const float* __restrict__ feat,
    const unsigned int* __restrict__ m2,
    const float* __restrict__ W_ih,
    const float* __restrict__ W_hh,
    const float* __restrict__ b_ih,
    const float* __restrict__ b_hh,
    const float* __restrict__ W_out,
    const float* __restrict__ b_out,
    float* __restrict__ out) {
    int n = blockIdx.x * 256 + threadIdx.x;
    if (n >= N_NODES) return;

    float mv[MSG], h[HID];
    {
        const uint4* mu = reinterpret_cast<const uint4*>(m2 + (size_t)n * 8);
        uint4 a = mu[0], b = mu[1];
        unsigned int w[8] = {a.x, a.y, a.z, a.w, b.x, b.y, b.z, b.w};
        #pragma unroll
        for (int i = 0; i < 8; ++i) {
            H2U hh;
            hh.u = w[i];
            mv[2 * i]     = (float)hh.h[0];
            mv[2 * i + 1] = (float)hh.h[1];
        }
        const float4* f4 = reinterpret_cast<const float4*>(feat + (size_t)n * HID);
        #pragma unroll
        for (int q = 0; q < 4; ++q) {
            float4 v = f4[q];
            h[q * 4 + 0] = v.x; h[q * 4 + 1] = v.y;
            h[q * 4 + 2] = v.z; h[q * 4 + 3] = v.w;
        }
    }

    float srz[2 * HID];
    for (int g = 0; g < 2 * HID; ++g) {
        float ai = 0.f, ah = 0.f;
        const float* wi = W_ih + g * MSG;
        const float* wh = W_hh + g * HID;
        #pragma unroll
        for (int k = 0; k < HID; ++k) {
            ai += wi[k] * mv[k];
            ah += wh[k] * h[k];
        }
        srz[g] = ai + ah + b_ih[g] + b_hh[g];
    }
    float i_n[HID], h_n[HID];
    #pragma unroll
    for (int j = 0; j < HID; ++j) {
        int g = 2 * HID + j;
        float ai = b_ih[g], ah = b_hh[g];
        const float* wi = W_ih + g * MSG;
        const float* wh = W_hh + g * HID;
        #pragma unroll
        for (int k = 0; k < HID; ++k) {
            ai += wi[k] * mv[k];
            ah += wh[k] * h[k];
        }
        i_n[j] = ai;
        h_n[j] = ah;
    }

    float hn[HID];
    #pragma unroll
    for (int j = 0; j < HID; ++j) {
        float r = fast_sigmoid(srz[j]);
        float z = fast_sigmoid(srz[HID + j]);
        float nn = fast_tanh(i_n[j] + r * h_n[j]);
        hn[j] = (1.f - z) * nn + z * h[j];
    }

    float4* op = reinterpret_cast<float4*>(out + (size_t)n * NC);
    #pragma unroll
    for (int c4 = 0; c4 < NC / 4; ++c4) {
        float4 o;
        float* oo = &o.x;
        #pragma unroll
        for (int cc = 0; cc < 4; ++cc) {
            int c = c4 * 4 + cc;
            float acc = b_out[c];
            const float* wo = W_out + c * HID;
            #pragma unroll
            for (int k = 0; k < HID; ++k) acc += wo[k] * hn[k];
            oo[cc] = acc;
        }
        op[c4] = o;
    }
}

extern "C" void kernel_launch(void* const* d_in, const int* in_sizes, int n_in,
                              void* d_out, int out_size, void* d_ws, size_t ws_size,
                              hipStream_t stream) {
    const float* feat       = (const float*)d_in[0];
    const int*   src        = (const int*)d_in[1];
    const int*   dst        = (const int*)d_in[2];
    const int*   etype      = (const int*)d_in[3];
    const float* edge_table = (const float*)d_in[4];
    const float* W_ih       = (const float*)d_in[5];
    const float* W_hh       = (const float*)d_in[6];
    const float* b_ih       = (const float*)d_in[7];
    const float* b_hh       = (const float*)d_in[8];
    const float* W_out      = (const float*)d_in[9];
    const float* b_out      = (const float*)d_in[10];
    float* out = (float*)d_out;

    // workspace layout (words): m2 [800K], feat16 [800K], A2 [1K],
    // bincnt [256], binbuf [200*12288 = 2.4576M]  -> ~16.3 MB
    unsigned int* m2     = (unsigned int*)d_ws;
    unsigned int* feat16 = m2 + PREP_N;
    unsigned int* A2     = feat16 + PREP_N;
    unsigned int* bincnt = A2 + A2_WORDS;
    unsigned int* binbuf = bincnt + 256;

    size_t need = ((size_t)PREP_N * 2 + A2_WORDS + 256 +
                   (size_t)NBIN * BCAP) * sizeof(unsigned int);

    int pblocks = (PREP_N + 255) / 256;                  // 3125
    int nblocks = (N_NODES + 255) / 256;                 // 391

    if (ws_size >= need) {
        // Binned two-pass path: zero global atomics in the reduction.
        ggnn_prep<<<pblocks, 256, 0, stream>>>(feat, edge_table, feat16,
                                               nullptr, A2, bincnt);
        int ablocks = (N_EDGES + CHUNK - 1) / CHUNK;     // 391
        ggnn_binA<<<ablocks, 256, 0, stream>>>(src, dst, etype, bincnt, binbuf);
        ggnn_pull2<<<NBIN, 512, 0, stream>>>(bincnt, binbuf, feat16, A2, m2);
        ggnn_node<<<nblocks, 256, 0, stream>>>(feat, m2, W_ih, W_hh, b_ih, b_hh,
                                               W_out, b_out, out);
    } else {
        // Fallback: proven round-0 atomic-scatter path.
        ggnn_prep<<<pblocks, 256, 0, stream>>>(feat, edge_table, feat16,
                                               m2, A2, nullptr);
        long long ethreads = (long long)N_EDGES * 8;     // 12.8M
        int eblocks = (int)((ethreads + 255) / 256);     // 50000
        ggnn_edge<<<eblocks, 256, 0, stream>>>(src, dst, etype, feat16, A2, m2);
        ggnn_node<<<nblocks, 256, 0, stream>>>(feat, m2, W_ih, W_hh, b_ih, b_hh,
                                               W_out, b_out, out);
    }
}